// Round 7
// baseline (2304.438 us; speedup 1.0000x reference)
//
#include <hip/hip_runtime.h>
#include <math.h>

namespace {

constexpr int BB = 8;
constexpr int LL = 768;
constexpr int DD = 512;
constexpr int L2E = LL * LL;
constexpr float NEGF = -1e9f;

__device__ __forceinline__ float softplus_f(float x) {
  return x > 0.f ? x + log1pf(expf(-x)) : log1pf(expf(x));
}
__device__ __forceinline__ float logsigmoid_f(float x) {
  return x > 0.f ? -log1pf(expf(-x)) : x - log1pf(expf(x));
}

// diag-compact: diag s = r + c (0-based), element index Jext(s, r)
__device__ __forceinline__ int doffc(int s) {
  return (s <= LL - 1) ? ((s * (s + 1)) >> 1)
                       : (L2E - (((2 * LL - 1 - s) * (2 * LL - s)) >> 1));
}
__device__ __forceinline__ int Jext(int s, int r) {
  return doffc(s) + r - ((s > LL - 1) ? (s - (LL - 1)) : 0);
}
__device__ __forceinline__ int dJa(int s) { return (s <= LL - 2) ? s + 1 : 2 * LL - 2 - s; }
__device__ __forceinline__ int dJd(int s) { return (s <= LL - 1) ? -s : s - (2 * LL - 1); }

// -------- Kernel A: out[r][c] = sum_d X[r][d] * W[c][d] + bias[c] --------
__global__ __launch_bounds__(256) void linear_kernel(
    const float* __restrict__ hx, const float* __restrict__ hy,
    const float* __restrict__ Wm, const float* __restrict__ bm,
    const float* __restrict__ Wg, const float* __restrict__ bg,
    float* __restrict__ zx, float* __restrict__ zy,
    float* __restrict__ gx, float* __restrict__ gy) {
  constexpr int BK = 16;
  __shared__ float Xs[BK][64 + 1];
  __shared__ float Ws[BK][64 + 1];

  const int which = blockIdx.z;
  const float* Xin  = (which & 1) ? hy : hx;
  const float* W    = (which >= 2) ? Wg : Wm;
  const float* bias = (which >= 2) ? bg : bm;
  float* out = (which == 0) ? zx : (which == 1) ? zy : (which == 2) ? gx : gy;

  const int row0 = blockIdx.y * 64;
  const int col0 = blockIdx.x * 64;
  const int t  = threadIdx.x;
  const int tx = t & 15;
  const int ty = t >> 4;
  const int lrow = t >> 2;
  const int lseg = (t & 3) * 4;

  float acc[4][4] = {};
  for (int k0 = 0; k0 < DD; k0 += BK) {
    const float4 xv = *(const float4*)(Xin + (size_t)(row0 + lrow) * DD + k0 + lseg);
    const float4 wv = *(const float4*)(W   + (size_t)(col0 + lrow) * DD + k0 + lseg);
    Xs[lseg + 0][lrow] = xv.x; Xs[lseg + 1][lrow] = xv.y;
    Xs[lseg + 2][lrow] = xv.z; Xs[lseg + 3][lrow] = xv.w;
    Ws[lseg + 0][lrow] = wv.x; Ws[lseg + 1][lrow] = wv.y;
    Ws[lseg + 2][lrow] = wv.z; Ws[lseg + 3][lrow] = wv.w;
    __syncthreads();
#pragma unroll
    for (int kk = 0; kk < BK; ++kk) {
      float xr[4], wr[4];
#pragma unroll
      for (int a = 0; a < 4; ++a) xr[a] = Xs[kk][ty * 4 + a];
#pragma unroll
      for (int b = 0; b < 4; ++b) wr[b] = Ws[kk][tx * 4 + b];
#pragma unroll
      for (int a = 0; a < 4; ++a)
#pragma unroll
        for (int b = 0; b < 4; ++b) acc[a][b] += xr[a] * wr[b];
    }
    __syncthreads();
  }
#pragma unroll
  for (int a = 0; a < 4; ++a) {
    const int r = row0 + ty * 4 + a;
#pragma unroll
    for (int b2 = 0; b2 < 4; ++b2) {
      const int c = col0 + tx * 4 + b2;
      out[(size_t)r * DD + c] = acc[a][b2] + bias[c];
    }
  }
}

// -------- Kernel B: theta/A batched logits --------
__global__ __launch_bounds__(256) void logits_kernel(
    const float* __restrict__ zx, const float* __restrict__ zy,
    const float* __restrict__ gx, const float* __restrict__ gy,
    float* __restrict__ theta, float* __restrict__ Aout) {
  constexpr int BK = 16;
  __shared__ float Xs[BK][64 + 1];
  __shared__ float Ys[BK][64 + 1];

  const int bz = blockIdx.z;
  const int b = bz >> 1, w = bz & 1;
  const float* X = (w ? gx : zx) + (size_t)b * LL * DD;
  const float* Y = (w ? gy : zy) + (size_t)b * LL * DD;
  float* out = (w ? Aout : theta) + (size_t)b * L2E;

  const int row0 = blockIdx.y * 64;
  const int col0 = blockIdx.x * 64;
  const int t  = threadIdx.x;
  const int tx = t & 15;
  const int ty = t >> 4;
  const int lrow = t >> 2;
  const int lseg = (t & 3) * 4;

  float acc[4][4] = {};
  for (int k0 = 0; k0 < DD; k0 += BK) {
    const float4 xv = *(const float4*)(X + (size_t)(row0 + lrow) * DD + k0 + lseg);
    const float4 yv = *(const float4*)(Y + (size_t)(col0 + lrow) * DD + k0 + lseg);
    Xs[lseg + 0][lrow] = xv.x; Xs[lseg + 1][lrow] = xv.y;
    Xs[lseg + 2][lrow] = xv.z; Xs[lseg + 3][lrow] = xv.w;
    Ys[lseg + 0][lrow] = yv.x; Ys[lseg + 1][lrow] = yv.y;
    Ys[lseg + 2][lrow] = yv.z; Ys[lseg + 3][lrow] = yv.w;
    __syncthreads();
#pragma unroll
    for (int kk = 0; kk < BK; ++kk) {
      float xr[4], yr[4];
#pragma unroll
      for (int a = 0; a < 4; ++a) xr[a] = Xs[kk][ty * 4 + a];
#pragma unroll
      for (int b2 = 0; b2 < 4; ++b2) yr[b2] = Ys[kk][tx * 4 + b2];
#pragma unroll
      for (int a = 0; a < 4; ++a)
#pragma unroll
        for (int b2 = 0; b2 < 4; ++b2) acc[a][b2] += xr[a] * yr[b2];
    }
    __syncthreads();
  }
#pragma unroll
  for (int a = 0; a < 4; ++a) {
    const int r = row0 + ty * 4 + a;
#pragma unroll
    for (int b2 = 0; b2 < 4; ++b2) {
      const int c = col0 + tx * 4 + b2;
      const float v = acc[a][b2];
      out[(size_t)r * LL + c] = w ? logsigmoid_f(v) : softplus_f(v);
    }
  }
}

// -------- row-major theta,A -> packed diag-compact float2 (th, a) --------
__global__ __launch_bounds__(256) void row2diag(
    const float* __restrict__ theta, const float* __restrict__ A,
    float2* __restrict__ thaa) {
  __shared__ float tT[64 * 66];
  __shared__ float tA[64 * 66];
  const int b = blockIdx.z;
  const float* inT = theta + (size_t)b * L2E;
  const float* inA = A + (size_t)b * L2E;
  float2* out = thaa + (size_t)b * L2E;
  const int r0 = blockIdx.y * 64, c0 = blockIdx.x * 64;
  const int t = threadIdx.x, lane = t & 63, grp = t >> 6;
  for (int it = 0; it < 16; ++it) {
    const int rr = it * 4 + grp;
    tT[rr * 66 + lane] = inT[(size_t)(r0 + rr) * LL + c0 + lane];
    tA[rr * 66 + lane] = inA[(size_t)(r0 + rr) * LL + c0 + lane];
  }
  __syncthreads();
  for (int si = grp; si < 127; si += 4) {
    const int s = r0 + c0 + si;
    const int rlo = max(r0, s - c0 - 63);
    const int rhi = min(r0 + 63, s - c0);
    const int r = rlo + lane;
    if (r <= rhi) {
      const int ii = (r - r0) * 66 + (s - r - c0);
      out[doffc(s) + r - max(0, s - (LL - 1))] = make_float2(tT[ii], tA[ii]);
    }
  }
}

// -------- diag-compact -> row-major (aln) --------
__global__ __launch_bounds__(256) void diag2row(
    const float* __restrict__ Ed, float* __restrict__ aln) {
  __shared__ float tile[64 * 66];
  const int b = blockIdx.z;
  const int r0 = blockIdx.y * 64;
  const int c0 = blockIdx.x * 64;
  const float* E = Ed + (size_t)b * L2E;
  float* out = aln + (size_t)b * L2E;
  const int t = threadIdx.x;
  const int lane = t & 63;
  const int grp = t >> 6;
  for (int si = grp; si < 127; si += 4) {
    const int s = r0 + c0 + si;
    const int rlo = max(r0, s - c0 - 63);
    const int rhi = min(r0 + 63, s - c0);
    const int r = rlo + lane;
    if (r <= rhi) {
      tile[(r - r0) * 66 + (s - r - c0)] = E[doffc(s) + r - max(0, s - (LL - 1))];
    }
  }
  __syncthreads();
  for (int it = 0; it < 16; ++it) {
    const int rr = it * 4 + grp;
    out[(size_t)(r0 + rr) * LL + c0 + lane] = tile[rr * 66 + lane];
  }
}

// -------- Fused NW fwd+bwd: 4 rows/lane, 3 waves, 32-deep shared rings --------
// Lane t owns rows 4t+1..4t+4. Boundary lanes read the SAME ring as intra-wave
// lanes (ring depth 32 > max cross-wave skew). Cross-wave sync: per-8-step
// producer-progress flags (Pf/Pb) + consumer-progress back-pressure (Cf/Cb)
// so the ring is never overrun. E overwrites V in place (E at s=k-2 written
// after last V read at s=k-6; descending order => read-before-write).
__global__ __launch_bounds__(192, 1) void nw_fused(
    const float2* __restrict__ thaa, float* __restrict__ VEd) {
  extern __shared__ float smf[];
  int* Pf = (int*)smf;          // [4] fwd producer progress (last k published)
  int* Cf = (int*)smf + 4;      // [4] fwd consumer progress (last k consumed)
  int* Pb = (int*)smf + 8;      // [4] bwd producer progress (descending)
  int* Cb = (int*)smf + 12;     // [4] bwd consumer progress (descending)
  float* RVf = smf + 16;        // [32][192] fwd V ring
  float* RVb = RVf + 32 * 192;  // [32][192] bwd V ring
  float* REb = RVb + 32 * 192;  // [32][192] bwd E ring

  const int b = blockIdx.x;
  const float2* TA = thaa + (size_t)b * L2E;
  float* V = VEd + (size_t)b * L2E;

  const int t = threadIdx.x;
  const int w = t >> 6, l = t & 63;
  const int rowb = 4 * t;
  const int kb = 256 * w + 2;
  const int ke = kb + 1023;

  if (t < 4) {
    Pf[t] = 0;            Cf[t] = 256 * t + 1;     // kb_t - 1
    Pb[t] = 0x7fffffff;   Cb[t] = 256 * t + 1026;  // ke_t + 1
  }
  __syncthreads();

  // ================= forward =================
  {
    float2 pq[4][4];
    int sL = kb - 2, iL = Jext(sL, rowb);
#pragma unroll
    for (int du = 0; du < 4; ++du) {
      const int slot = (2 + du) & 3;
#pragma unroll
      for (int r = 0; r < 4; ++r) pq[slot][r] = TA[iL + r];
      iL += dJa(sL); ++sL;
    }
    int sS = kb - 2, iS = Jext(sS, rowb);
    float p1[4], p2[4];
#pragma unroll
    for (int r = 0; r < 4; ++r) { p1[r] = NEGF; p2[r] = NEGF; }
    float rvh = NEGF;
    const int rdT = (t == 0) ? 0 : (t - 1);

    for (int kg = kb; kg < kb + 1024; kg += 8) {
      if (l == 0 && w > 0 && kg < kb + 768) {
        const int need = min(kg + 6, kb + 766);
        while (__hip_atomic_load(&Pf[w - 1], __ATOMIC_ACQUIRE,
                                 __HIP_MEMORY_SCOPE_WORKGROUP) < need) {}
      }
      if (l == 63 && w < 2) {  // back-pressure: don't overrun consumer by >24
        while (__hip_atomic_load(&Cf[w + 1], __ATOMIC_ACQUIRE,
                                 __HIP_MEMORY_SCOPE_WORKGROUP) < kg - 24) {}
      }
#pragma unroll
      for (int u = 0; u < 8; ++u) {
        const int k = kg + u;
        const int su = (2 + u) & 3;
        const int k31 = k & 31, m31 = (k - 1) & 31;
        float rv = RVf[m31 * 192 + rdT];
        if (l == 0 && w == 0) rv = NEGF;
        float rdg = rvh;
        if (l == 0 && w == 0) rdg = (k == 2) ? 0.f : NEGF;
        const int d = k - rowb - 2;
        float vv[4];
#pragma unroll
        for (int r = 0; r < 4; ++r) {
          const float Vl = p1[r];
          const float Vu = (r == 0) ? rv : p1[r - 1];
          const float Vg = (r == 0) ? rdg : p2[r - 1];
          const float av = pq[su][r].y, tv = pq[su][r].x;
          const float lft = av + Vl, up = av + Vu;
          const float mx = fmaxf(Vg, fmaxf(lft, up));
          const float val = tv + mx +
              __logf(__expf(Vg - mx) + __expf(lft - mx) + __expf(up - mx));
          vv[r] = ((unsigned)(d - r) <= 767u) ? val : NEGF;
        }
#pragma unroll
        for (int r = 0; r < 4; ++r) pq[su][r] = TA[iL + r];  // for step k+4
        iL += dJa(sL); ++sL;
#pragma unroll
        for (int r = 0; r < 4; ++r)
          if ((unsigned)(d - r) <= 767u) V[iS + r] = vv[r];
        iS += dJa(sS); ++sS;
        RVf[k31 * 192 + t] = vv[3];
        rvh = rv;
#pragma unroll
        for (int r = 0; r < 4; ++r) { p2[r] = p1[r]; p1[r] = vv[r]; }
        asm volatile("" ::: "memory");
      }
      if (l == 63 && w < 2)
        __hip_atomic_store(&Pf[w], kg + 7, __ATOMIC_RELEASE,
                           __HIP_MEMORY_SCOPE_WORKGROUP);
      if (l == 0 && w > 0)
        __hip_atomic_store(&Cf[w], kg + 7, __ATOMIC_RELEASE,
                           __HIP_MEMORY_SCOPE_WORKGROUP);
    }
  }
  __syncthreads();

  // ================= backward =================
  {
    float sVv[4][4];     // V at s=k-2, rows rowb..rowb+3
    float sKt[4][4];     // th at s=k,  rows rowb+1..rowb+4
    float2 sK1[4][5];    // (th, a) at s=k-1, rows rowb..rowb+4
    int sV_ = ke - 2, iV = Jext(sV_, rowb);
    int sKc = ke,     iK = Jext(sKc, rowb);
    int sK1s = ke - 1, iK1 = Jext(sK1s, rowb);
#pragma unroll
    for (int du = 0; du < 4; ++du) {
      const int slot = (1 - du) & 3;
#pragma unroll
      for (int r = 0; r < 4; ++r) sVv[slot][r] = V[iV + r];
#pragma unroll
      for (int r = 0; r < 4; ++r) sKt[slot][r] = TA[iK + 1 + r].x;
#pragma unroll
      for (int r = 0; r < 5; ++r) sK1[slot][r] = TA[iK1 + r];
      iV += dJd(sV_); --sV_;
      iK += dJd(sKc); --sKc;
      iK1 += dJd(sK1s); --sK1s;
    }
    int sE = ke - 2, iE = Jext(sE, rowb);
    float N1v[4], N1e[4], N2v[4], N2e[4], hV[4], hE[4];
#pragma unroll
    for (int r = 0; r < 4; ++r) {
      N1v[r] = 0.f; N1e[r] = 0.f; N2v[r] = 0.f; N2e[r] = 0.f; hV[r] = 0.f; hE[r] = 0.f;
    }
    const int rdU = (t == 191) ? 191 : (t + 1);

    for (int kg = ke; kg > ke - 1024; kg -= 8) {
      if (l == 63 && w < 2 && kg >= kb + 255) {
        const int need = max(kg - 6, kb + 256);
        while (__hip_atomic_load(&Pb[w + 1], __ATOMIC_ACQUIRE,
                                 __HIP_MEMORY_SCOPE_WORKGROUP) > need) {}
      }
      if (l == 0 && w > 0) {  // back-pressure vs consumer below
        while (__hip_atomic_load(&Cb[w - 1], __ATOMIC_ACQUIRE,
                                 __HIP_MEMORY_SCOPE_WORKGROUP) > kg + 23) {}
      }
#pragma unroll
      for (int u = 0; u < 8; ++u) {
        const int k = kg - u;
        const int su = (1 - u) & 3;
        const int k31 = k & 31, p31 = (k + 1) & 31;
        N1v[3] = RVb[p31 * 192 + rdU];
        N1e[3] = REb[p31 * 192 + rdU];
        const int d = k - rowb - 2;
        float e[4], vc[4];
#pragma unroll
        for (int r = 0; r < 4; ++r) {
          vc[r] = sVv[su][r];
          const bool ok  = (unsigned)(d - r) <= 767u;
          const bool jlt = (d - r) < 767;
          const bool ilt = (rowb + r) < 767;
          float acc = 0.f;
          if (ilt && jlt) acc += N2e[r] * __expf(vc[r] - N2v[r] + sKt[su][r]);
          if (jlt) acc += hE[r] * __expf(sK1[su][r].y + vc[r] - hV[r] + sK1[su][r].x);
          if (ilt) acc += N1e[r] * __expf(sK1[su][r + 1].y + vc[r] - N1v[r] + sK1[su][r + 1].x);
          e[r] = ok ? acc : 0.f;
        }
        if (k == 2 * LL && t == 191) e[3] = 1.f;
        // refills for step k-4
#pragma unroll
        for (int r = 0; r < 4; ++r) sVv[su][r] = V[iV + r];
#pragma unroll
        for (int r = 0; r < 4; ++r) sKt[su][r] = TA[iK + 1 + r].x;
#pragma unroll
        for (int r = 0; r < 5; ++r) sK1[su][r] = TA[iK1 + r];
        iV += dJd(sV_); --sV_;
        iK += dJd(sKc); --sKc;
        iK1 += dJd(sK1s); --sK1s;
        // E store (s = k-2), masked; overwrites V (read-before-write, descending)
#pragma unroll
        for (int r = 0; r < 4; ++r)
          if ((unsigned)(d - r) <= 767u) V[iE + r] = e[r];
        iE += dJd(sE); --sE;
        RVb[k31 * 192 + t] = vc[0];
        REb[k31 * 192 + t] = e[0];
#pragma unroll
        for (int r = 0; r < 4; ++r) { N2v[r] = N1v[r]; N2e[r] = N1e[r]; }
        N1v[0] = vc[1]; N1e[0] = e[1];
        N1v[1] = vc[2]; N1e[1] = e[2];
        N1v[2] = vc[3]; N1e[2] = e[3];
#pragma unroll
        for (int r = 0; r < 4; ++r) { hV[r] = vc[r]; hE[r] = e[r]; }
        asm volatile("" ::: "memory");
      }
      if (l == 0 && w > 0)
        __hip_atomic_store(&Pb[w], kg - 7, __ATOMIC_RELEASE,
                           __HIP_MEMORY_SCOPE_WORKGROUP);
      if (l == 63 && w < 2)
        __hip_atomic_store(&Cb[w], kg - 7, __ATOMIC_RELEASE,
                           __HIP_MEMORY_SCOPE_WORKGROUP);
    }
  }
}

}  // namespace

extern "C" void kernel_launch(void* const* d_in, const int* in_sizes, int n_in,
                              void* d_out, int out_size, void* d_ws, size_t ws_size,
                              hipStream_t stream) {
  const float* hx = (const float*)d_in[0];
  const float* hy = (const float*)d_in[1];
  const float* Wm = (const float*)d_in[2];
  const float* bm = (const float*)d_in[3];
  const float* Wg = (const float*)d_in[4];
  const float* bg = (const float*)d_in[5];

  float* aln   = (float*)d_out;
  float* theta = aln + (size_t)BB * L2E;
  float* A     = theta + (size_t)BB * L2E;

  // phase-2 workspace: packed (th,a) float2 diag array + V/E (in-place)
  float2* thaa = (float2*)d_ws;
  float*  VEd  = (float*)d_ws + (size_t)BB * L2E * 2;
  // phase-1 workspace aliases the same region (dead after logits)
  float* zx = (float*)d_ws;
  float* zy = zx + (size_t)BB * LL * DD;
  float* gx = zy + (size_t)BB * LL * DD;
  float* gy = gx + (size_t)BB * LL * DD;

  linear_kernel<<<dim3(DD / 64, (BB * LL) / 64, 4), 256, 0, stream>>>(
      hx, hy, Wm, bm, Wg, bg, zx, zy, gx, gy);
  logits_kernel<<<dim3(LL / 64, LL / 64, BB * 2), 256, 0, stream>>>(
      zx, zy, gx, gy, theta, A);
  row2diag<<<dim3(LL / 64, LL / 64, BB), 256, 0, stream>>>(theta, A, thaa);

  const size_t SH = (size_t)(16 + 3 * 32 * 192) * sizeof(float);  // 73,792 B
  nw_fused<<<dim3(BB), 192, SH, stream>>>(thaa, VEd);

  diag2row<<<dim3(LL / 64, LL / 64, BB), 256, 0, stream>>>(VEd, aln);
}